// Round 2
// baseline (644.706 us; speedup 1.0000x reference)
//
#include <hip/hip_runtime.h>

// PSA fused window attention, MI355X gfx950.
// One block = one window (64 tokens). 4 waves. bf16 MFMA 16x16x32 everywhere.
// Fragment maps (learn_hip m89/m91 verified):
//   A/B operand: [lane&15][ (lane>>4)*8 + j ]   (8 contiguous bf16 in K)
//   C/D:         row = (lane>>4)*4 + reg, col = lane&15

typedef unsigned short u16;
typedef short bf16x8 __attribute__((ext_vector_type(8)));
typedef short bf16x4 __attribute__((ext_vector_type(4)));
typedef float f32x4  __attribute__((ext_vector_type(4)));

__device__ __forceinline__ f32x4 mfma_bf16(bf16x8 a, bf16x8 b, f32x4 c) {
  return __builtin_amdgcn_mfma_f32_16x16x32_bf16(a, b, c, 0, 0, 0);
}

#define SCALE_F 0.1767766952966369f  // (256/8)^-0.5

__device__ __forceinline__ u16 f2b(float f) {           // fp32 -> bf16 RNE
  unsigned u = __builtin_bit_cast(unsigned, f);
  u = (u + 0x7FFFu + ((u >> 16) & 1u)) >> 16;
  return (u16)u;
}
__device__ __forceinline__ float b2f(u16 h) {
  return __builtin_bit_cast(float, (unsigned)h << 16);
}

// ---- d_ws layout (u16 element offsets) ----
#define WS_WQKV   0        // [384][256] bf16: rows 0-127 q_w, 128-255 K(kv_w), 256-383 V
#define WS_WPROJ  98304    // [256][128] bf16
#define WS_BIASPK 131072   // [h8][w4][lane64][16] bf16, C-frag packed rel-pos bias
#define WS_MASKPK 163840   // [nw64][w4][lane64][16] bf16, C-frag packed mask
#define WS_QKVB   425984   // [384] bf16 (q_b ++ kv_b)
#define WS_TOTAL  426368

__global__ void psa_prep(const float* __restrict__ qw, const float* __restrict__ qb,
                         const float* __restrict__ kvw, const float* __restrict__ kvb,
                         const float* __restrict__ projw, const float* __restrict__ bt,
                         const int* __restrict__ ri, const float* __restrict__ mask,
                         u16* __restrict__ ws) {
  int i = blockIdx.x * 256 + threadIdx.x;
  if (i < 98304) {
    int r = i >> 8, c = i & 255;
    ws[WS_WQKV + i] = f2b(r < 128 ? qw[r * 256 + c] : kvw[(r - 128) * 256 + c]);
  } else if (i < 131072) {
    int j = i - 98304;
    ws[WS_WPROJ + j] = f2b(projw[j]);
  } else if (i < 163840) {
    int j = i - 131072;   // bias_pk: j = h*4096 + w*1024 + lane*16 + t,  t = nt*4 + r
    int t = j & 15, lane = (j >> 4) & 63, w = (j >> 10) & 3, h = j >> 12;
    int row = w * 16 + (lane >> 4) * 4 + (t & 3);
    int col = (t >> 2) * 16 + (lane & 15);
    ws[WS_BIASPK + j] = f2b(bt[ri[row * 64 + col] * 8 + h]);
  } else if (i < 425984) {
    int j = i - 163840;   // mask_pk: j = nw*4096 + w*1024 + lane*16 + t
    int t = j & 15, lane = (j >> 4) & 63, w = (j >> 10) & 3, nw = j >> 12;
    int row = w * 16 + (lane >> 4) * 4 + (t & 3);
    int col = (t >> 2) * 16 + (lane & 15);
    ws[WS_MASKPK + j] = f2b(mask[(nw * 64 + row) * 64 + col]);
  } else if (i < WS_TOTAL) {
    int j = i - 425984;
    ws[WS_QKVB + j] = f2b(j < 128 ? qb[j] : kvb[j - 128]);
  }
}

__global__ __launch_bounds__(256, 2) void psa_main(
    const float* __restrict__ x, const float* __restrict__ proj_b,
    const u16* __restrict__ ws, float* __restrict__ out) {
  // LDS: 33792 + 18432 + 9216 = 61440 B  -> 2 blocks/CU
  __shared__ u16 qks[64 * 264];   // [tok][264]: cols 0-127 Q (later O), 128-255 K; stride 132w==4 mod 32
  __shared__ u16 vsm[8 * 16 * 72];// [h][hd][tok72]: V transposed (B-operand layout for PV)
  __shared__ u16 scr[64 * 72];    // phase2: x bf16 K-chunk [64][72]; phase3-5: per-wave P slabs

  const int win = blockIdx.x;
  const int tid = threadIdx.x;
  const int wave = tid >> 6;
  const int lane = tid & 63;
  const int quad = lane >> 4;
  const int n16  = lane & 15;
  const int nw   = win & 63;

  const f32x4 zero4 = {0.f, 0.f, 0.f, 0.f};
  const float* xw = x + (size_t)win * 16384;

  // ================= Phase 2: QKV = Xw @ Wqkv^T (M=64,N=384,K=256) ===========
  f32x4 acc[6][4];
  #pragma unroll
  for (int nt = 0; nt < 6; ++nt)
    #pragma unroll
    for (int mt = 0; mt < 4; ++mt) acc[nt][mt] = zero4;

  const int col0 = wave * 96;     // each wave owns 6 N-tiles (96 cols of 384)
  for (int kc = 0; kc < 4; ++kc) {      // K chunks of 64
    __syncthreads();                    // previous chunk fully read
    #pragma unroll
    for (int it = 0; it < 4; ++it) {    // stage x[:, kc*64 .. +64) as bf16
      int idx = it * 256 + tid;
      int row = idx >> 4, c4 = (idx & 15) * 4;
      float4 v = *(const float4*)(xw + row * 256 + kc * 64 + c4);
      bf16x4 pk;
      pk[0] = (short)f2b(v.x); pk[1] = (short)f2b(v.y);
      pk[2] = (short)f2b(v.z); pk[3] = (short)f2b(v.w);
      *(bf16x4*)&scr[row * 72 + c4] = pk;
    }
    __syncthreads();
    #pragma unroll
    for (int ks = 0; ks < 2; ++ks) {
      bf16x8 af[4];
      #pragma unroll
      for (int mt = 0; mt < 4; ++mt)
        af[mt] = *(const bf16x8*)&scr[(mt * 16 + n16) * 72 + ks * 32 + quad * 8];
      #pragma unroll
      for (int nt = 0; nt < 6; ++nt) {
        bf16x8 bw = *(const bf16x8*)&ws[WS_WQKV + (col0 + nt * 16 + n16) * 256 + kc * 64 + ks * 32 + quad * 8];
        #pragma unroll
        for (int mt = 0; mt < 4; ++mt) acc[nt][mt] = mfma_bf16(af[mt], bw, acc[nt][mt]);
      }
    }
  }
  // writeback: Q,K -> qks ; V -> vsm (transposed)
  #pragma unroll
  for (int nt = 0; nt < 6; ++nt) {
    int col = col0 + nt * 16 + n16;
    float badd = b2f(ws[WS_QKVB + col]);
    if (col < 256) {
      #pragma unroll
      for (int mt = 0; mt < 4; ++mt)
        #pragma unroll
        for (int r = 0; r < 4; ++r)
          qks[(mt * 16 + quad * 4 + r) * 264 + col] = f2b(acc[nt][mt][r] + badd);
    } else {
      int vc = col - 256, vh = vc >> 4, vd = vc & 15;
      #pragma unroll
      for (int mt = 0; mt < 4; ++mt)
        #pragma unroll
        for (int r = 0; r < 4; ++r)
          vsm[vh * 1152 + vd * 72 + mt * 16 + quad * 4 + r] = f2b(acc[nt][mt][r] + badd);
    }
  }
  __syncthreads();

  // ====== Phase 3-5: per-head S = QK^T -> softmax -> O = P V  ================
  // wave w owns token rows [16w,16w+16) for ALL heads; O overwrites Q cols.
  const int kq = (quad & 1) * 8;  // quads 2,3 read same addr as 0,1; operand zeroed
  const u16* bpk = ws + WS_BIASPK + (wave * 64 + lane) * 16;
  const u16* mpk = ws + WS_MASKPK + ((nw * 4 + wave) * 64 + lane) * 16;
  bf16x8 mm0 = *(const bf16x8*)mpk;
  bf16x8 mm1 = *(const bf16x8*)(mpk + 8);

  #pragma unroll 1
  for (int h = 0; h < 8; ++h) {
    bf16x8 aq = (bf16x8){0, 0, 0, 0, 0, 0, 0, 0};
    if (quad < 2) aq = *(const bf16x8*)&qks[(wave * 16 + n16) * 264 + h * 16 + kq];
    f32x4 s[4];
    #pragma unroll
    for (int nt = 0; nt < 4; ++nt) {
      bf16x8 bk = (bf16x8){0, 0, 0, 0, 0, 0, 0, 0};
      if (quad < 2) bk = *(const bf16x8*)&qks[(nt * 16 + n16) * 264 + 128 + h * 16 + kq];
      s[nt] = mfma_bf16(aq, bk, zero4);
    }
    bf16x8 bm0 = *(const bf16x8*)(bpk + h * 4096);
    bf16x8 bm1 = *(const bf16x8*)(bpk + h * 4096 + 8);

    float pe[4][4];   // [nt][r] unnormalized exp
    float rinv[4];
    #pragma unroll
    for (int r = 0; r < 4; ++r) {
      float l[4];
      #pragma unroll
      for (int nt = 0; nt < 4; ++nt) {
        int t = nt * 4 + r;
        float bv = b2f((u16)(t < 8 ? bm0[t] : bm1[t - 8]));
        float mv = b2f((u16)(t < 8 ? mm0[t] : mm1[t - 8]));
        l[nt] = s[nt][r] * SCALE_F + bv + mv;
      }
      float mx = fmaxf(fmaxf(l[0], l[1]), fmaxf(l[2], l[3]));
      mx = fmaxf(mx, __shfl_xor(mx, 1));
      mx = fmaxf(mx, __shfl_xor(mx, 2));
      mx = fmaxf(mx, __shfl_xor(mx, 4));
      mx = fmaxf(mx, __shfl_xor(mx, 8));
      float sum = 0.f;
      #pragma unroll
      for (int nt = 0; nt < 4; ++nt) {
        float e = __expf(l[nt] - mx);
        pe[nt][r] = e; sum += e;
      }
      sum += __shfl_xor(sum, 1);
      sum += __shfl_xor(sum, 2);
      sum += __shfl_xor(sum, 4);
      sum += __shfl_xor(sum, 8);
      rinv[r] = __builtin_amdgcn_rcpf(sum);
      #pragma unroll
      for (int nt = 0; nt < 4; ++nt)
        scr[(wave * 16 + quad * 4 + r) * 72 + nt * 16 + n16] = f2b(pe[nt][r]);
    }
    // PV: A = P slab (A-layout from scr), B = V^T (vsm). Same-wave LDS RAW: DS in-order.
    f32x4 o = zero4;
    #pragma unroll
    for (int ks = 0; ks < 2; ++ks) {
      bf16x8 ap = *(const bf16x8*)&scr[(wave * 16 + n16) * 72 + ks * 32 + quad * 8];
      bf16x8 bv = *(const bf16x8*)&vsm[h * 1152 + n16 * 72 + ks * 32 + quad * 8];
      o = mfma_bf16(ap, bv, o);
    }
    #pragma unroll
    for (int r = 0; r < 4; ++r)   // O/l -> overwrite own Q cols (proj A-layout)
      qks[(wave * 16 + quad * 4 + r) * 264 + h * 16 + n16] = f2b(o[r] * rinv[r]);
  }
  __syncthreads();

  // ================= Phase 6: out = O @ Wproj^T + proj_b =====================
  f32x4 po[4][4];
  #pragma unroll
  for (int nt = 0; nt < 4; ++nt)
    #pragma unroll
    for (int mt = 0; mt < 4; ++mt) po[nt][mt] = zero4;
  #pragma unroll
  for (int ks = 0; ks < 4; ++ks) {
    bf16x8 af[4];
    #pragma unroll
    for (int mt = 0; mt < 4; ++mt)
      af[mt] = *(const bf16x8*)&qks[(mt * 16 + n16) * 264 + ks * 32 + quad * 8];
    #pragma unroll
    for (int nt = 0; nt < 4; ++nt) {
      bf16x8 bw = *(const bf16x8*)&ws[WS_WPROJ + (wave * 64 + nt * 16 + n16) * 128 + ks * 32 + quad * 8];
      #pragma unroll
      for (int mt = 0; mt < 4; ++mt) po[nt][mt] = mfma_bf16(af[mt], bw, po[nt][mt]);
    }
  }
  float* ow = out + (size_t)win * 16384;
  #pragma unroll
  for (int nt = 0; nt < 4; ++nt) {
    int coln = wave * 64 + nt * 16 + n16;
    float pb = proj_b[coln];
    #pragma unroll
    for (int mt = 0; mt < 4; ++mt)
      #pragma unroll
      for (int r = 0; r < 4; ++r)
        ow[(mt * 16 + quad * 4 + r) * 256 + coln] = po[nt][mt][r] + pb;
  }
}

extern "C" void kernel_launch(void* const* d_in, const int* in_sizes, int n_in,
                              void* d_out, int out_size, void* d_ws, size_t ws_size,
                              hipStream_t stream) {
  (void)in_sizes; (void)n_in; (void)out_size; (void)ws_size;
  const float* x    = (const float*)d_in[0];
  const float* mask = (const float*)d_in[1];
  const float* qw   = (const float*)d_in[2];
  const float* qb   = (const float*)d_in[3];
  const float* kvw  = (const float*)d_in[4];
  const float* kvb  = (const float*)d_in[5];
  const float* pw   = (const float*)d_in[6];
  const float* pb   = (const float*)d_in[7];
  const float* bt   = (const float*)d_in[8];
  const int*   ri   = (const int*)d_in[9];
  u16* ws = (u16*)d_ws;

  psa_prep<<<(WS_TOTAL + 255) / 256, 256, 0, stream>>>(qw, qb, kvw, kvb, pw, bt, ri, mask, ws);
  psa_main<<<4096, 256, 0, stream>>>(x, pb, ws, (float*)d_out);
}